// Round 5
// baseline (124.706 us; speedup 1.0000x reference)
//
#include <hip/hip_runtime.h>

// QuantumPINN: out = a*z + b, z = <psi| Z |psi>, psi = U(weights) RY(x)|0>.
// Algebraic collapse: out = K0 + K1*cos(x) + K2*sin(x) = K0 + R*cos(x - phi).
// Single dispatch. Per element: fma (radians->revolutions + phase) -> v_cos_f32
// -> fma. Unroll-4 (4 KB/wave in flight), NT loads AND stores (both streams
// are touch-once; bypass L2/L3 fill occupancy).

// Native clang vector (HIP's float4 is a class; nontemporal builtins need this).
typedef float f32x4 __attribute__((ext_vector_type(4)));

struct cplx { float re, im; };

__device__ inline cplx cmul(cplx p, cplx q) {
    return cplx{p.re * q.re - p.im * q.im, p.re * q.im + p.im * q.re};
}
__device__ inline cplx cadd(cplx p, cplx q) { return cplx{p.re + q.re, p.im + q.im}; }

// Accurate coefficient computation (ONE thread per block; ~0.1us, amortized).
__device__ inline void qpinn_coeffs(const float* __restrict__ w, float a, float b,
                                    float& K0, float& R, float& mphirev) {
    cplx U00{1.f, 0.f}, U01{0.f, 0.f}, U10{0.f, 0.f}, U11{1.f, 0.f};
    #pragma unroll
    for (int l = 0; l < 2; ++l) {
        const float h0 = 0.5f * w[3 * l + 0];
        const float h1 = 0.5f * w[3 * l + 1];
        const float h2 = 0.5f * w[3 * l + 2];
        float c0, s0, c1, s1, c2, s2;
        sincosf(h0, &s0, &c0);
        sincosf(h1, &s1, &c1);
        sincosf(h2, &s2, &c2);

        cplx X00{c0, 0.f}, X01{0.f, -s0}, X10{0.f, -s0}, X11{c0, 0.f};
        cplx Y00{c1, 0.f}, Y01{-s1, 0.f}, Y10{s1, 0.f}, Y11{c1, 0.f};
        cplx A00 = cadd(cmul(Y00, X00), cmul(Y01, X10));
        cplx A01 = cadd(cmul(Y00, X01), cmul(Y01, X11));
        cplx A10 = cadd(cmul(Y10, X00), cmul(Y11, X10));
        cplx A11 = cadd(cmul(Y10, X01), cmul(Y11, X11));
        cplx zm{c2, -s2}, zp{c2, s2};
        cplx L00 = cmul(zm, A00), L01 = cmul(zm, A01);
        cplx L10 = cmul(zp, A10), L11 = cmul(zp, A11);
        cplx n00 = cadd(cmul(L00, U00), cmul(L01, U10));
        cplx n01 = cadd(cmul(L00, U01), cmul(L01, U11));
        cplx n10 = cadd(cmul(L10, U00), cmul(L11, U10));
        cplx n11 = cadd(cmul(L10, U01), cmul(L11, U11));
        U00 = n00; U01 = n01; U10 = n10; U11 = n11;
    }
    const float A = (U00.re * U00.re + U00.im * U00.im) - (U10.re * U10.re + U10.im * U10.im);
    const float B = (U01.re * U01.re + U01.im * U01.im) - (U11.re * U11.re + U11.im * U11.im);
    const float C = 2.f * ((U00.re * U01.re + U00.im * U01.im) -
                           (U10.re * U11.re + U10.im * U11.im));
    K0 = fmaf(a, 0.5f * (A + B), b);
    const float K1 = a * 0.5f * (A - B);
    const float K2 = a * 0.5f * C;
    R = sqrtf(K1 * K1 + K2 * K2);
    const float INV2PI = 0.15915494309189535f;
    mphirev = -atan2f(K2, K1) * INV2PI;   // phase in revolutions (v_cos_f32 units)
}

__device__ inline f32x4 qpinn_elem4(f32x4 v, float K0, float R, float mph) {
    const float INV2PI = 0.15915494309189535f;
    f32x4 r;
    // |x| < ~6 => |t| < 1 revolution, inside v_cos_f32's exact range.
    r.x = fmaf(R, __builtin_amdgcn_cosf(fmaf(v.x, INV2PI, mph)), K0);
    r.y = fmaf(R, __builtin_amdgcn_cosf(fmaf(v.y, INV2PI, mph)), K0);
    r.z = fmaf(R, __builtin_amdgcn_cosf(fmaf(v.z, INV2PI, mph)), K0);
    r.w = fmaf(R, __builtin_amdgcn_cosf(fmaf(v.w, INV2PI, mph)), K0);
    return r;
}

__global__ __launch_bounds__(256) void qpinn_fused(
    const float* __restrict__ x, const float* __restrict__ w,
    const float* __restrict__ pa, const float* __restrict__ pb,
    float* __restrict__ out, int n4) {

    __shared__ float sc[3];
    if (threadIdx.x == 0) {
        float K0, R, mph;
        qpinn_coeffs(w, pa[0], pb[0], K0, R, mph);
        sc[0] = K0; sc[1] = R; sc[2] = mph;
    }
    __syncthreads();
    const float K0 = sc[0];   // same-address LDS read -> broadcast
    const float R  = sc[1];
    const float mph = sc[2];

    const f32x4* __restrict__ x4 = (const f32x4*)x;
    f32x4* __restrict__ o4 = (f32x4*)out;

    const int stride = gridDim.x * blockDim.x;
    int i = blockIdx.x * blockDim.x + threadIdx.x;

    // Unroll-4: four independent 1KB/wave NT loads in flight per iteration.
    // n4 = 8*stride exactly at the launch config below -> 2 full iterations.
    for (; i + 3 * stride < n4; i += 4 * stride) {
        const int i1 = i + stride, i2 = i + 2 * stride, i3 = i + 3 * stride;
        f32x4 v0 = __builtin_nontemporal_load(&x4[i]);
        f32x4 v1 = __builtin_nontemporal_load(&x4[i1]);
        f32x4 v2 = __builtin_nontemporal_load(&x4[i2]);
        f32x4 v3 = __builtin_nontemporal_load(&x4[i3]);
        f32x4 r0 = qpinn_elem4(v0, K0, R, mph);
        f32x4 r1 = qpinn_elem4(v1, K0, R, mph);
        f32x4 r2 = qpinn_elem4(v2, K0, R, mph);
        f32x4 r3 = qpinn_elem4(v3, K0, R, mph);
        __builtin_nontemporal_store(r0, &o4[i]);
        __builtin_nontemporal_store(r1, &o4[i1]);
        __builtin_nontemporal_store(r2, &o4[i2]);
        __builtin_nontemporal_store(r3, &o4[i3]);
    }
    for (; i < n4; i += stride) {
        f32x4 v0 = __builtin_nontemporal_load(&x4[i]);
        f32x4 r0 = qpinn_elem4(v0, K0, R, mph);
        __builtin_nontemporal_store(r0, &o4[i]);
    }
}

extern "C" void kernel_launch(void* const* d_in, const int* in_sizes, int n_in,
                              void* d_out, int out_size, void* d_ws, size_t ws_size,
                              hipStream_t stream) {
    const float* x = (const float*)d_in[0];
    const float* w = (const float*)d_in[1];   // [L=2, 3]
    const float* a = (const float*)d_in[2];
    const float* b = (const float*)d_in[3];
    float* out = (float*)d_out;

    const int n = in_sizes[0];       // 16777216, divisible by 4
    const int n4 = n / 4;            // 4194304 float4 elements
    const int block = 256;
    // 8 blocks/CU (256 CU): 32 waves/CU full occupancy; 8 float4/thread.
    const int grid = 2048;

    qpinn_fused<<<grid, block, 0, stream>>>(x, w, a, b, out, n4);
}

// Round 6
// 113.070 us; speedup vs baseline: 1.1029x; 1.1029x over previous
//
#include <hip/hip_runtime.h>

// QuantumPINN: out = a*z + b, z = <psi| Z |psi>, psi = U(weights) RY(x)|0>.
// Algebraic collapse: out = K0 + K1*cos(x) + K2*sin(x) = K0 + R*cos(x - phi).
// Single dispatch. Per element: fma (radians->revolutions + phase) -> v_cos_f32
// -> fma. 1 trans + 2 VALU per element, unroll-2 for MLP, NT stores only.
// (R5 A/B: NT loads and/or unroll-4 cost +12us — reverted. NT stores +
// 1-trans collapse are the proven levers: 115.7 -> 113.1 us.)

// Native clang vector (HIP's float4 is a class; nontemporal builtin needs this).
typedef float f32x4 __attribute__((ext_vector_type(4)));

struct cplx { float re, im; };

__device__ inline cplx cmul(cplx p, cplx q) {
    return cplx{p.re * q.re - p.im * q.im, p.re * q.im + p.im * q.re};
}
__device__ inline cplx cadd(cplx p, cplx q) { return cplx{p.re + q.re, p.im + q.im}; }

// Accurate coefficient computation (runs on ONE thread per block; ~0.1us).
__device__ inline void qpinn_coeffs(const float* __restrict__ w, float a, float b,
                                    float& K0, float& R, float& mphirev) {
    cplx U00{1.f, 0.f}, U01{0.f, 0.f}, U10{0.f, 0.f}, U11{1.f, 0.f};
    #pragma unroll
    for (int l = 0; l < 2; ++l) {
        const float h0 = 0.5f * w[3 * l + 0];
        const float h1 = 0.5f * w[3 * l + 1];
        const float h2 = 0.5f * w[3 * l + 2];
        float c0, s0, c1, s1, c2, s2;
        sincosf(h0, &s0, &c0);
        sincosf(h1, &s1, &c1);
        sincosf(h2, &s2, &c2);

        cplx X00{c0, 0.f}, X01{0.f, -s0}, X10{0.f, -s0}, X11{c0, 0.f};
        cplx Y00{c1, 0.f}, Y01{-s1, 0.f}, Y10{s1, 0.f}, Y11{c1, 0.f};
        cplx A00 = cadd(cmul(Y00, X00), cmul(Y01, X10));
        cplx A01 = cadd(cmul(Y00, X01), cmul(Y01, X11));
        cplx A10 = cadd(cmul(Y10, X00), cmul(Y11, X10));
        cplx A11 = cadd(cmul(Y10, X01), cmul(Y11, X11));
        cplx zm{c2, -s2}, zp{c2, s2};
        cplx L00 = cmul(zm, A00), L01 = cmul(zm, A01);
        cplx L10 = cmul(zp, A10), L11 = cmul(zp, A11);
        cplx n00 = cadd(cmul(L00, U00), cmul(L01, U10));
        cplx n01 = cadd(cmul(L00, U01), cmul(L01, U11));
        cplx n10 = cadd(cmul(L10, U00), cmul(L11, U10));
        cplx n11 = cadd(cmul(L10, U01), cmul(L11, U11));
        U00 = n00; U01 = n01; U10 = n10; U11 = n11;
    }
    const float A = (U00.re * U00.re + U00.im * U00.im) - (U10.re * U10.re + U10.im * U10.im);
    const float B = (U01.re * U01.re + U01.im * U01.im) - (U11.re * U11.re + U11.im * U11.im);
    const float C = 2.f * ((U00.re * U01.re + U00.im * U01.im) -
                           (U10.re * U11.re + U10.im * U11.im));
    K0 = fmaf(a, 0.5f * (A + B), b);
    const float K1 = a * 0.5f * (A - B);
    const float K2 = a * 0.5f * C;
    R = sqrtf(K1 * K1 + K2 * K2);
    const float INV2PI = 0.15915494309189535f;
    mphirev = -atan2f(K2, K1) * INV2PI;   // phase in revolutions (v_cos_f32 units)
}

__device__ inline f32x4 qpinn_elem4(f32x4 v, float K0, float R, float mph) {
    const float INV2PI = 0.15915494309189535f;
    f32x4 r;
    // |x| < ~6 => |t| < 1 revolution, inside v_cos_f32's exact range.
    r.x = fmaf(R, __builtin_amdgcn_cosf(fmaf(v.x, INV2PI, mph)), K0);
    r.y = fmaf(R, __builtin_amdgcn_cosf(fmaf(v.y, INV2PI, mph)), K0);
    r.z = fmaf(R, __builtin_amdgcn_cosf(fmaf(v.z, INV2PI, mph)), K0);
    r.w = fmaf(R, __builtin_amdgcn_cosf(fmaf(v.w, INV2PI, mph)), K0);
    return r;
}

__global__ __launch_bounds__(256) void qpinn_fused(
    const float* __restrict__ x, const float* __restrict__ w,
    const float* __restrict__ pa, const float* __restrict__ pb,
    float* __restrict__ out, int n4) {

    __shared__ float sc[3];
    if (threadIdx.x == 0) {
        float K0, R, mph;
        qpinn_coeffs(w, pa[0], pb[0], K0, R, mph);
        sc[0] = K0; sc[1] = R; sc[2] = mph;
    }
    __syncthreads();
    const float K0 = sc[0];   // same-address LDS read -> broadcast
    const float R  = sc[1];
    const float mph = sc[2];

    const f32x4* __restrict__ x4 = (const f32x4*)x;
    f32x4* __restrict__ o4 = (f32x4*)out;

    const int stride = gridDim.x * blockDim.x;
    int i = blockIdx.x * blockDim.x + threadIdx.x;

    // Unroll-2: two independent 1KB/wave loads in flight per iteration (2x MLP).
    for (; i + stride < n4; i += 2 * stride) {
        const int j = i + stride;
        f32x4 v0 = x4[i];
        f32x4 v1 = x4[j];
        f32x4 r0 = qpinn_elem4(v0, K0, R, mph);
        f32x4 r1 = qpinn_elem4(v1, K0, R, mph);
        // NT stores: out is write-once, never re-read -> don't pollute L2/L3
        __builtin_nontemporal_store(r0, &o4[i]);
        __builtin_nontemporal_store(r1, &o4[j]);
    }
    if (i < n4) {
        f32x4 v0 = x4[i];
        f32x4 r0 = qpinn_elem4(v0, K0, R, mph);
        __builtin_nontemporal_store(r0, &o4[i]);
    }
}

extern "C" void kernel_launch(void* const* d_in, const int* in_sizes, int n_in,
                              void* d_out, int out_size, void* d_ws, size_t ws_size,
                              hipStream_t stream) {
    const float* x = (const float*)d_in[0];
    const float* w = (const float*)d_in[1];   // [L=2, 3]
    const float* a = (const float*)d_in[2];
    const float* b = (const float*)d_in[3];
    float* out = (float*)d_out;

    const int n = in_sizes[0];       // 16777216, divisible by 4
    const int n4 = n / 4;            // 4194304 float4 elements
    const int block = 256;
    // 8 blocks/CU (256 CU): 32 waves/CU full occupancy; 8 float4/thread.
    const int grid = 2048;

    qpinn_fused<<<grid, block, 0, stream>>>(x, w, a, b, out, n4);
}